// Round 12
// baseline (470.043 us; speedup 1.0000x reference)
//
#include <hip/hip_runtime.h>
#include <math.h>

// Problem constants (match reference)
#define NB   64     // num_groups (B)
#define NG   32     // group_size (G)
#define ND   2000   // output dim D
#define NM   16     // m_samples
#define NE   16     // noise dim
#define NDIN 256
#define NK   272    // DIN + E

#define XR_OFF 512  // smem layout: wred [0..511], xr [512..512+8704)

__device__ __forceinline__ float clampf(float v, float lo, float hi) {
    return fminf(fmaxf(v, lo), hi);
}

__device__ __forceinline__ float softplusf(float v) {
    return (v > 20.f) ? v : log1pf(expf(v));
}

// Broadcast lane `lane`'s value wave-uniformly (lives in SGPR).
__device__ __forceinline__ float readlane_f(float v, int lane) {
    return __int_as_float(__builtin_amdgcn_readlane(__float_as_int(v), lane));
}

// Fully-packed butterfly: reduce v[0..31] across 64 lanes in 32 shuffles.
// Returns the wave total for g = (lane>>1)&31 (dup on lane pairs).
// HW-verified rounds 3-11.
__device__ __forceinline__ float wave_sum32(float v[NG], int lane) {
    {   const bool hi = (lane & 32) != 0;
        #pragma unroll
        for (int k = 0; k < 16; ++k) {
            float s = hi ? v[k] : v[k + 16];
            float r = __shfl_xor(s, 32);
            v[k] = (hi ? v[k + 16] : v[k]) + r;
        }
    }
    {   const bool hi = (lane & 16) != 0;
        #pragma unroll
        for (int k = 0; k < 8; ++k) {
            float s = hi ? v[k] : v[k + 8];
            float r = __shfl_xor(s, 16);
            v[k] = (hi ? v[k + 8] : v[k]) + r;
        }
    }
    {   const bool hi = (lane & 8) != 0;
        #pragma unroll
        for (int k = 0; k < 4; ++k) {
            float s = hi ? v[k] : v[k + 4];
            float r = __shfl_xor(s, 8);
            v[k] = (hi ? v[k + 4] : v[k]) + r;
        }
    }
    {   const bool hi = (lane & 4) != 0;
        #pragma unroll
        for (int k = 0; k < 2; ++k) {
            float s = hi ? v[k] : v[k + 2];
            float r = __shfl_xor(s, 4);
            v[k] = (hi ? v[k + 2] : v[k]) + r;
        }
    }
    {   const bool hi = (lane & 2) != 0;
        float s = hi ? v[0] : v[1];
        float r = __shfl_xor(s, 2);
        v[0] = (hi ? v[1] : v[0]) + r;
    }
    v[0] += __shfl_xor(v[0], 1);
    return v[0];
}

// ---------------------------------------------------------------------------
// Mega kernel: grid 576 x 512 threads, __launch_bounds__(512, 1).
//   blocks 0..63   : FUSED xpred-GEMM + IPF + integerization (b = blockIdx.x)
//   blocks 64..575 : loss partials (8 d-chunks x 64 b)
// Round-11 lesson: the standalone xpred kernel cost ~120 us and was
// insensitive to prefetch/occupancy — so we DELETE it: each IPF block
// computes its own 32x2000 y0 tile in-register (32 rows x 272 k GEMM from
// LDS-staged x rows), overlapped with the loss blocks on the other CUs.
// No xp workspace, no handoff (round-10: resident spinners lose), no
// extra kernel boundary.  IPF iterations/epilogue are round-9 verbatim
// (182 us, VGPR 84, zero spill under LB(512,1) + SGPR-B via readlane).
// ---------------------------------------------------------------------------

// ---- fused IPF path: thread owns d = 4t..4t+3 full-column (all 32 g) ----
__device__ __forceinline__ void ipf_path(
        const float* __restrict__ x, const float* __restrict__ nsamp,
        const float* __restrict__ W, const float* __restrict__ bias,
        const int* __restrict__ tsum, float* __restrict__ out,
        float* smem, int b, int t) {
    const int lane = t & 63, w = t >> 6;      // wave 0..7
    const int d0 = t * 4;
    const bool valid = (d0 < ND);             // t < 500
    const int g_own = (lane >> 1) & 31;

    float* wred = smem;                       // [2][8][32] floats, dbuf
    float* xr   = smem + XR_OFF;              // [32][272] staged x||noise rows

    // ---- stage this b's 32 rows of concat(x, noise_sample) into LDS ----
    for (int idx = t; idx < NG * NK; idx += 512) {
        const int g = idx / NK, c = idx - g * NK;
        const int row = b * NG + g;
        xr[idx] = (c < NDIN) ? x[(size_t)row * NDIN + c]
                             : nsamp[(size_t)row * NE + (c - NDIN)];
    }
    __syncthreads();

    // ---- in-register xpred GEMM: y0[j][g] = relu(softplus(sum_k xr*W + b)) -
    // Same per-4k accumulation expression as the old k3 (y0 bit-compatible).
    float y0r[4][NG];
    #pragma unroll
    for (int j = 0; j < 4; ++j)
        #pragma unroll
        for (int g = 0; g < NG; ++g) y0r[j][g] = 0.f;

    if (valid) {
        for (int k = 0; k < NK; k += 4) {
            float4 wk[4];
            #pragma unroll
            for (int kk = 0; kk < 4; ++kk)
                wk[kk] = *(const float4*)&W[(size_t)(k + kk) * ND + d0];
            #pragma unroll
            for (int g = 0; g < NG; ++g) {
                const float4 xv = *(const float4*)&xr[g * NK + k];
                y0r[0][g] += xv.x * wk[0].x + xv.y * wk[1].x + xv.z * wk[2].x + xv.w * wk[3].x;
                y0r[1][g] += xv.x * wk[0].y + xv.y * wk[1].y + xv.z * wk[2].y + xv.w * wk[3].y;
                y0r[2][g] += xv.x * wk[0].z + xv.y * wk[1].z + xv.z * wk[2].z + xv.w * wk[3].z;
                y0r[3][g] += xv.x * wk[0].w + xv.y * wk[1].w + xv.z * wk[2].w + xv.w * wk[3].w;
            }
        }
        const float4 bv = *(const float4*)&bias[d0];
        #pragma unroll
        for (int g = 0; g < NG; ++g) {
            y0r[0][g] = fmaxf(softplusf(y0r[0][g] + bv.x), 0.f);
            y0r[1][g] = fmaxf(softplusf(y0r[1][g] + bv.y), 0.f);
            y0r[2][g] = fmaxf(softplusf(y0r[2][g] + bv.z), 0.f);
            y0r[3][g] = fmaxf(softplusf(y0r[3][g] + bv.w), 0.f);
        }
    }
    float Cc[4] = {0.f, 0.f, 0.f, 0.f};
    if (valid) {
        const int4 ci = *(const int4*)(tsum + (size_t)b * ND + d0);
        Cc[0] = (float)ci.x; Cc[1] = (float)ci.y; Cc[2] = (float)ci.z; Cc[3] = (float)ci.w;
    }
    float Ac[4] = {1.f, 1.f, 1.f, 1.f};
    float Bown = 1.f;                         // lane-pair's B[g_own]
    float Rown;                               // lane-pair's R[g_own]

    // prologue: row anchors R (buf 0)
    {
        float v[NG];
        #pragma unroll
        for (int g = 0; g < NG; ++g)
            v[g] = y0r[0][g] + y0r[1][g] + y0r[2][g] + y0r[3][g];
        const float tot = wave_sum32(v, lane);
        if ((lane & 1) == 0) wred[w * NG + g_own] = tot;
        __syncthreads();
        float s = 0.f;
        #pragma unroll
        for (int w2 = 0; w2 < 8; ++w2) s += wred[w2 * NG + g_own];
        Rown = s;
    }

    // 60 IPF iterations, ONE barrier each (double-buffered wred)
    for (int q = 1; q <= 60; ++q) {
        // column phase (thread-local; B broadcast via readlane -> SGPRs)
        float s0 = 0.f, s1 = 0.f, s2 = 0.f, s3 = 0.f;
        #pragma unroll
        for (int g = 0; g < NG; ++g) {
            const float bg = readlane_f(Bown, 2 * g);
            s0 += y0r[0][g] * bg; s1 += y0r[1][g] * bg;
            s2 += y0r[2][g] * bg; s3 += y0r[3][g] * bg;
        }
        Ac[0] *= clampf(Cc[0] / fmaxf(Ac[0] * s0, 1e-12f), 0.75f, 1.25f);
        Ac[1] *= clampf(Cc[1] / fmaxf(Ac[1] * s1, 1e-12f), 0.75f, 1.25f);
        Ac[2] *= clampf(Cc[2] / fmaxf(Ac[2] * s2, 1e-12f), 0.75f, 1.25f);
        Ac[3] *= clampf(Cc[3] / fmaxf(Ac[3] * s3, 1e-12f), 0.75f, 1.25f);
        // row phase
        float v[NG];
        #pragma unroll
        for (int g = 0; g < NG; ++g)
            v[g] = y0r[0][g] * Ac[0] + y0r[1][g] * Ac[1]
                 + y0r[2][g] * Ac[2] + y0r[3][g] * Ac[3];
        const float tot = wave_sum32(v, lane);
        const int buf = (q & 1) * (8 * NG);
        if ((lane & 1) == 0) wred[buf + w * NG + g_own] = tot;
        __syncthreads();
        float s = 0.f;
        #pragma unroll
        for (int w2 = 0; w2 < 8; ++w2) s += wred[buf + w2 * NG + g_own];
        Bown *= clampf(Rown / fmaxf(Bown * s, 1e-12f), 0.75f, 1.25f);
    }

    // epilogue: final scale + exact integerization, thread-local per d.
    // Rank-based neg branch (reference-equivalent): no dynamic indexing.
    if (!valid) return;

    unsigned pk[NG];
    #pragma unroll
    for (int g = 0; g < NG; ++g) pk[g] = 0u;

    #pragma unroll
    for (int j = 0; j < 4; ++j) {
        float fr[NG];
        int   yv[NG];
        float s = 0.f;
        #pragma unroll
        for (int g = 0; g < NG; ++g) {
            const float z = y0r[j][g] * Ac[j] * readlane_f(Bown, 2 * g);
            fr[g] = z;
            s += z;
        }
        const float F = Cc[j] / fmaxf(s, 1e-12f);
        int isum = 0;
        #pragma unroll
        for (int g = 0; g < NG; ++g) {
            const float y = fr[g] * F;
            const float fl = floorf(y);
            yv[g] = (int)fl;
            fr[g] = y - fl;
            isum += yv[g];
        }
        const int Ci = (int)Cc[j];
        const int need = Ci - isum;
        const int pos = max(need, 0);
        const int q = pos >> 5;
        const int r = pos & 31;
        #pragma unroll
        for (int g = 0; g < NG; ++g) yv[g] += q;
        #pragma unroll
        for (int g = 0; g < NG; ++g) {       // stable DESCENDING rank on frac
            int rank = 0;
            #pragma unroll
            for (int h = 0; h < NG; ++h) {
                if (h == g) continue;
                rank += (h < g) ? (fr[h] >= fr[g] ? 1 : 0) : (fr[h] > fr[g] ? 1 : 0);
            }
            if (rank < r) yv[g] += 1;
        }
        // negative residual: one-shot ascending rank among yv>0 (== reference)
        int neg = max(-need, 0);
        neg = min(neg, isum);
        if (__builtin_expect(neg > 0, 0)) {
            const int q2 = neg >> 5;
            int removed = 0;
            #pragma unroll
            for (int g = 0; g < NG; ++g) {
                const int yb = yv[g];
                const int yn = max(yb - q2, 0);
                removed += yb - yn;
                yv[g] = yn;
            }
            const int r2 = neg - removed;
            if (r2 > 0) {
                const float INF = __builtin_inff();
                #pragma unroll
                for (int g = 0; g < NG; ++g) {
                    const float fg = (yv[g] > 0) ? fr[g] : INF;
                    int rank = 0;
                    #pragma unroll
                    for (int h = 0; h < NG; ++h) {
                        if (h == g) continue;
                        const float fh = (yv[h] > 0) ? fr[h] : INF;
                        rank += (h < g) ? (fh <= fg ? 1 : 0) : (fh < fg ? 1 : 0);
                    }
                    if (rank < r2) yv[g] = max(yv[g] - 1, 0);
                }
            }
        }
        #pragma unroll
        for (int g = 0; g < NG; ++g)
            pk[g] |= ((unsigned)yv[g]) << (8 * j);   // yv <= C <= 199 < 256
    }
    #pragma unroll
    for (int g = 0; g < NG; ++g) {
        float* op = &out[1 + (size_t)(b * NG + g) * ND + d0];
        op[0] = (float)(pk[g] & 0xffu);
        op[1] = (float)((pk[g] >> 8) & 0xffu);
        op[2] = (float)((pk[g] >> 16) & 0xffu);
        op[3] = (float)((pk[g] >> 24) & 0xffu);
    }
}

// ---- loss-partials path: 512 blocks = 8 d-chunks x 64 b (round-9 exact) ---
__device__ __forceinline__ void loss_path(
        const float* __restrict__ x, const float* __restrict__ nl,
        const float* __restrict__ tgt, const float* __restrict__ W,
        const float* __restrict__ bias, float* __restrict__ res2,
        float* smem, int cx, int b, int t) {
    float* xsl = smem;                 // 256
    float* nsl = smem + 256;           // 256
    float* tgl = smem + 512;           // 252
    float* pt  = smem + 764;           // 16 x 252

    if (t < 256) {
        const float* xb = x + (size_t)b * NG * NDIN;
        float s = 0.f;
        for (int g = 0; g < NG; ++g) s += xb[g * NDIN + t];
        xsl[t] = s;
        const float* nb = nl + (size_t)b * NG * (NM * NE);
        float s2 = 0.f;
        for (int g = 0; g < NG; ++g) s2 += nb[g * (NM * NE) + t];
        nsl[t] = s2;
    }

    int tm = 0, tn = 0;
    if (t >= 16 && t < 152) {
        int p = t - 16;
        for (int m = 0; m < NM; ++m) {
            int c = NM - m;
            if (p < c) { tm = m; tn = m + p; break; }
            p -= c;
        }
    }
    __syncthreads();

    const int d = cx * 250 + t;
    if (t < 250) {
        tgl[t] = tgt[b * ND + d];
        float xw = 0.f;
        #pragma unroll 8
        for (int k = 0; k < NDIN; ++k) xw += xsl[k] * W[(size_t)k * ND + d];
        float we[NE];
        #pragma unroll
        for (int e = 0; e < NE; ++e) we[e] = W[(size_t)(NDIN + e) * ND + d];
        const float base0 = xw + (float)NG * bias[d];
        #pragma unroll
        for (int m = 0; m < NM; ++m) {
            float pm = base0;
            #pragma unroll
            for (int e = 0; e < NE; ++e) pm += nsl[m * NE + e] * we[e];
            pt[m * 252 + t] = pm;
        }
    }
    if (t < 32) {                      // zero-pad cols 250,251
        pt[(t >> 1) * 252 + 250 + (t & 1)] = 0.f;
        if (t < 2) tgl[250 + t] = 0.f;
    }
    __syncthreads();

    float acc = 0.f;
    if (t < 16) {
        const float4* pa  = (const float4*)&pt[t * 252];
        const float4* tga = (const float4*)&tgl[0];
        for (int i = 0; i < 63; ++i) {
            float4 pv = pa[i], tv = tga[i];
            float e0 = pv.x - tv.x, e1 = pv.y - tv.y, e2 = pv.z - tv.z, e3 = pv.w - tv.w;
            acc += e0 * e0 + e1 * e1 + e2 * e2 + e3 * e3;
        }
    } else if (t < 152) {
        const float4* pa = (const float4*)&pt[tm * 252];
        const float4* pb = (const float4*)&pt[tn * 252];
        for (int i = 0; i < 63; ++i) {
            float4 u = pa[i], v = pb[i];
            acc += u.x * v.x + u.y * v.y + u.z * v.z + u.w * v.w;
        }
    }
    if (t < 152) res2[((size_t)b * 8 + cx) * 152 + t] = acc;
}

extern "C" __global__ __launch_bounds__(512, 1)
void mega(const float* __restrict__ x, const float* __restrict__ nl,
          const float* __restrict__ tgt, const float* __restrict__ W,
          const float* __restrict__ bias, const float* __restrict__ nsamp,
          const int* __restrict__ tsum, float* __restrict__ out,
          float* __restrict__ res2) {
    __shared__ float smem[XR_OFF + NG * NK];   // 36.9 KB (ipf), loss uses 19.2
    const int bid = blockIdx.x;
    const int t = threadIdx.x;
    if (bid < NB) {
        ipf_path(x, nsamp, W, bias, tsum, out, smem, bid, t);
    } else {
        const int q = bid - NB;        // 0..511 -> 8 chunks x 64 b
        loss_path(x, nl, tgt, W, bias, res2, smem, q & 7, q >> 3, t);
    }
}

// K2b (single block): combine 8 chunk-partials per b, per-b loss, reduce
// over b, write out[0] directly (no atomics, no memset needed).
extern "C" __global__ __launch_bounds__(512)
void k2b_single(const float* __restrict__ res2, float* __restrict__ out) {
    __shared__ float ls[NB * 152];     // 38.9 KB
    const int t = threadIdx.x;
    for (int idx = t; idx < NB * 152; idx += 512) {
        const int b = idx / 152, tau = idx - b * 152;
        float s = 0.f;
        #pragma unroll
        for (int c = 0; c < 8; ++c) s += res2[((size_t)b * 8 + c) * 152 + tau];
        ls[idx] = s;
    }
    __syncthreads();
    float v = 0.f;
    if (t < NB) {
        const float* res = &ls[t * 152];
        float conf = 0.f;
        for (int m = 0; m < NM; ++m) conf += sqrtf(res[m]);
        conf *= (1.f / NM);
        float pd = 0.f;
        for (int m = 0; m < NM; ++m) {
            const int offm = 16 + m * NM - m * (m - 1) / 2;
            const float sqm = res[offm];
            for (int n = m + 1; n < NM; ++n) {
                const int offn = 16 + n * NM - n * (n - 1) / 2;
                const float sqn = res[offn];
                const float inn = res[offm + (n - m)];
                pd += sqrtf(fmaxf(sqm + sqn - 2.f * inn, 1e-6f));
            }
        }
        pd = 2.f * pd / (float)(NM * (NM - 1));
        v = (conf - 0.5f * pd) * (1.f / NB);
    }
    // wave-0 butterfly over the 64 per-b values
    if (t < 64) {
        #pragma unroll
        for (int o = 32; o >= 1; o >>= 1) v += __shfl_xor(v, o);
        if (t == 0) out[0] = v;
    }
}

// ---------------------------------------------------------------------------
extern "C" void kernel_launch(void* const* d_in, const int* in_sizes, int n_in,
                              void* d_out, int out_size, void* d_ws, size_t ws_size,
                              hipStream_t stream) {
    const float* x     = (const float*)d_in[0];
    const float* tgt   = (const float*)d_in[1];
    const int*   tsum  = (const int*)d_in[2];
    const float* W     = (const float*)d_in[3];
    const float* bias  = (const float*)d_in[4];
    const float* nl    = (const float*)d_in[5];
    const float* nsamp = (const float*)d_in[6];
    float* out  = (float*)d_out;
    float* res2 = (float*)d_ws;                        // 64*8*152 floats

    (void)in_sizes; (void)n_in; (void)out_size; (void)ws_size;

    hipLaunchKernelGGL(mega, dim3(NB + 512), dim3(512), 0, stream,
                       x, nl, tgt, W, bias, nsamp, tsum, out, res2);
    hipLaunchKernelGGL(k2b_single, dim3(1), dim3(512), 0, stream, res2, out);
}

// Round 13
// 337.813 us; speedup vs baseline: 1.3914x; 1.3914x over previous
//
#include <hip/hip_runtime.h>
#include <math.h>

// Problem constants (match reference)
#define NB   64     // num_groups (B)
#define NG   32     // group_size (G)
#define ND   2000   // output dim D
#define NM   16     // m_samples
#define NE   16     // noise dim
#define NDIN 256
#define NK   272    // DIN + E

__device__ __forceinline__ float clampf(float v, float lo, float hi) {
    return fminf(fmaxf(v, lo), hi);
}

__device__ __forceinline__ float softplusf(float v) {
    return (v > 20.f) ? v : log1pf(expf(v));
}

// Broadcast lane `lane`'s value wave-uniformly (lives in SGPR).
__device__ __forceinline__ float readlane_f(float v, int lane) {
    return __int_as_float(__builtin_amdgcn_readlane(__float_as_int(v), lane));
}

// Fully-packed butterfly: reduce v[0..31] across 64 lanes in 32 shuffles.
// Returns the wave total for g = (lane>>1)&31 (dup on lane pairs).
// HW-verified rounds 3-12.
__device__ __forceinline__ float wave_sum32(float v[NG], int lane) {
    {   const bool hi = (lane & 32) != 0;
        #pragma unroll
        for (int k = 0; k < 16; ++k) {
            float s = hi ? v[k] : v[k + 16];
            float r = __shfl_xor(s, 32);
            v[k] = (hi ? v[k + 16] : v[k]) + r;
        }
    }
    {   const bool hi = (lane & 16) != 0;
        #pragma unroll
        for (int k = 0; k < 8; ++k) {
            float s = hi ? v[k] : v[k + 8];
            float r = __shfl_xor(s, 16);
            v[k] = (hi ? v[k + 8] : v[k]) + r;
        }
    }
    {   const bool hi = (lane & 8) != 0;
        #pragma unroll
        for (int k = 0; k < 4; ++k) {
            float s = hi ? v[k] : v[k + 4];
            float r = __shfl_xor(s, 8);
            v[k] = (hi ? v[k + 4] : v[k]) + r;
        }
    }
    {   const bool hi = (lane & 4) != 0;
        #pragma unroll
        for (int k = 0; k < 2; ++k) {
            float s = hi ? v[k] : v[k + 2];
            float r = __shfl_xor(s, 4);
            v[k] = (hi ? v[k + 2] : v[k]) + r;
        }
    }
    {   const bool hi = (lane & 2) != 0;
        float s = hi ? v[0] : v[1];
        float r = __shfl_xor(s, 2);
        v[0] = (hi ? v[1] : v[0]) + r;
    }
    v[0] += __shfl_xor(v[0], 1);
    return v[0];
}

// ---------------------------------------------------------------------------
// Kernel A: 512 blocks x 512 threads.  Block q -> (cx = q&7, b = q>>3).
// Phase 1: xpred for batch b's 32 rows over d-window [cx*250, cx*250+250)
//          (W traffic = 272 KB/block, L2-hot; whole chip participates —
//          round-12 lesson: don't put this GEMM on the 64 IPF CUs).
// Phase 2: loss partials for (cx, b), reusing the LDS-staged x rows for the
//          g-sums.  Accumulation chains identical to rounds 9-11 =>
//          xp and res2 bit-identical.
// ---------------------------------------------------------------------------
extern "C" __global__ __launch_bounds__(512)
void k_front(const float* __restrict__ x, const float* __restrict__ nl,
             const float* __restrict__ tgt, const float* __restrict__ W,
             const float* __restrict__ bias, const float* __restrict__ nsamp,
             float* __restrict__ xp, float* __restrict__ res2) {
    __shared__ __align__(16) float xr[NG * NK];   // 8704 floats (34.8 KB)
    __shared__ __align__(16) float ls[4800];      // xsl/nsl/tgl/pt (19.2 KB)
    const int q  = blockIdx.x;
    const int cx = q & 7, b = q >> 3;
    const int t  = threadIdx.x;

    // ---- stage b's 32 rows of concat(x, noise_sample) ----
    for (int idx = t; idx < NG * NK; idx += 512) {
        const int g = idx / NK, c = idx - g * NK;
        const int row = b * NG + g;
        xr[idx] = (c < NDIN) ? x[(size_t)row * NDIN + c]
                             : nsamp[(size_t)row * NE + (c - NDIN)];
    }
    __syncthreads();

    // ---- phase 1: xpred.  t<500: d = cx*250 + (t>>1), 16 rows (t&1 half) --
    if (t < 500) {
        const int d  = cx * 250 + (t >> 1);
        const int r0 = (t & 1) << 4;         // rows 0..15 or 16..31
        float acc[16];
        #pragma unroll
        for (int r = 0; r < 16; ++r) acc[r] = 0.f;
        for (int k = 0; k < NK; k += 4) {
            const float w0 = W[(size_t)(k + 0) * ND + d];
            const float w1 = W[(size_t)(k + 1) * ND + d];
            const float w2 = W[(size_t)(k + 2) * ND + d];
            const float w3 = W[(size_t)(k + 3) * ND + d];
            #pragma unroll
            for (int r = 0; r < 16; ++r) {
                const float4 xv = *(const float4*)&xr[(r0 + r) * NK + k];
                acc[r] += xv.x * w0 + xv.y * w1 + xv.z * w2 + xv.w * w3;
            }
        }
        const float bv = bias[d];
        #pragma unroll
        for (int r = 0; r < 16; ++r)
            xp[(size_t)(b * NG + r0 + r) * ND + d] = softplusf(acc[r] + bv);
    }

    // ---- g-sums for the loss (xsl from LDS xr — same values & add order;
    //      nsl from noise_loss global) ----
    if (t < 256) {
        float s = 0.f;
        for (int g = 0; g < NG; ++g) s += xr[g * NK + t];
        ls[t] = s;                                        // xsl
        const float* nb = nl + (size_t)b * NG * (NM * NE);
        float s2 = 0.f;
        for (int g = 0; g < NG; ++g) s2 += nb[g * (NM * NE) + t];
        ls[256 + t] = s2;                                 // nsl
    }

    int tm = 0, tn = 0;
    if (t >= 16 && t < 152) {
        int p = t - 16;
        for (int m = 0; m < NM; ++m) {
            int c = NM - m;
            if (p < c) { tm = m; tn = m + p; break; }
            p -= c;
        }
    }
    __syncthreads();

    // ---- phase 2: loss partials (round-9 loss_path verbatim, ls offsets) --
    float* xsl = ls;                 // 256
    float* nsl = ls + 256;           // 256
    float* tgl = ls + 512;           // 252
    float* pt  = ls + 764;           // 16 x 252

    const int d = cx * 250 + t;
    if (t < 250) {
        tgl[t] = tgt[b * ND + d];
        float xw = 0.f;
        #pragma unroll 8
        for (int k = 0; k < NDIN; ++k) xw += xsl[k] * W[(size_t)k * ND + d];
        float we[NE];
        #pragma unroll
        for (int e = 0; e < NE; ++e) we[e] = W[(size_t)(NDIN + e) * ND + d];
        const float base0 = xw + (float)NG * bias[d];
        #pragma unroll
        for (int m = 0; m < NM; ++m) {
            float pm = base0;
            #pragma unroll
            for (int e = 0; e < NE; ++e) pm += nsl[m * NE + e] * we[e];
            pt[m * 252 + t] = pm;
        }
    }
    if (t < 32) {                      // zero-pad cols 250,251
        pt[(t >> 1) * 252 + 250 + (t & 1)] = 0.f;
        if (t < 2) tgl[250 + t] = 0.f;
    }
    __syncthreads();

    float acc = 0.f;
    if (t < 16) {
        const float4* pa  = (const float4*)&pt[t * 252];
        const float4* tga = (const float4*)&tgl[0];
        for (int i = 0; i < 63; ++i) {
            float4 pv = pa[i], tv = tga[i];
            float e0 = pv.x - tv.x, e1 = pv.y - tv.y, e2 = pv.z - tv.z, e3 = pv.w - tv.w;
            acc += e0 * e0 + e1 * e1 + e2 * e2 + e3 * e3;
        }
    } else if (t < 152) {
        const float4* pa = (const float4*)&pt[tm * 252];
        const float4* pb = (const float4*)&pt[tn * 252];
        for (int i = 0; i < 63; ++i) {
            float4 u = pa[i], v = pb[i];
            acc += u.x * v.x + u.y * v.y + u.z * v.z + u.w * v.w;
        }
    }
    if (t < 152) res2[((size_t)b * 8 + cx) * 152 + t] = acc;
}

// ---------------------------------------------------------------------------
// Kernel B: 65 blocks x 512 threads, __launch_bounds__(512, 1).
//   blocks 0..63 : IPF + integerization (round-9 verbatim: 182 us, VGPR 84)
//   block  64    : loss combine, single block (round-12 style: writes out[0]
//                  directly, no atomics/memset) — hidden under IPF's wall.
// IPF blocks now have the chip to themselves (no loss-block contention).
// ---------------------------------------------------------------------------
__device__ __forceinline__ void ipf_path(
        const float* __restrict__ xp, const int* __restrict__ tsum,
        float* __restrict__ out, float* smem, int b, int t) {
    const int lane = t & 63, w = t >> 6;      // wave 0..7
    const int d0 = t * 4;
    const bool valid = (d0 < ND);             // t < 500
    const int g_own = (lane >> 1) & 31;

    float* wred = smem;                       // [2][8][32] floats, dbuf

    float y0r[4][NG];
    #pragma unroll
    for (int g = 0; g < NG; ++g) {
        float4 v = make_float4(0.f, 0.f, 0.f, 0.f);
        if (valid) v = *(const float4*)(xp + (size_t)(b * NG + g) * ND + d0);
        y0r[0][g] = fmaxf(v.x, 0.f);
        y0r[1][g] = fmaxf(v.y, 0.f);
        y0r[2][g] = fmaxf(v.z, 0.f);
        y0r[3][g] = fmaxf(v.w, 0.f);
    }
    float Cc[4] = {0.f, 0.f, 0.f, 0.f};
    if (valid) {
        const int4 ci = *(const int4*)(tsum + (size_t)b * ND + d0);
        Cc[0] = (float)ci.x; Cc[1] = (float)ci.y; Cc[2] = (float)ci.z; Cc[3] = (float)ci.w;
    }
    float Ac[4] = {1.f, 1.f, 1.f, 1.f};
    float Bown = 1.f;
    float Rown;

    {
        float v[NG];
        #pragma unroll
        for (int g = 0; g < NG; ++g)
            v[g] = y0r[0][g] + y0r[1][g] + y0r[2][g] + y0r[3][g];
        const float tot = wave_sum32(v, lane);
        if ((lane & 1) == 0) wred[w * NG + g_own] = tot;
        __syncthreads();
        float s = 0.f;
        #pragma unroll
        for (int w2 = 0; w2 < 8; ++w2) s += wred[w2 * NG + g_own];
        Rown = s;
    }

    for (int q = 1; q <= 60; ++q) {
        float s0 = 0.f, s1 = 0.f, s2 = 0.f, s3 = 0.f;
        #pragma unroll
        for (int g = 0; g < NG; ++g) {
            const float bg = readlane_f(Bown, 2 * g);
            s0 += y0r[0][g] * bg; s1 += y0r[1][g] * bg;
            s2 += y0r[2][g] * bg; s3 += y0r[3][g] * bg;
        }
        Ac[0] *= clampf(Cc[0] / fmaxf(Ac[0] * s0, 1e-12f), 0.75f, 1.25f);
        Ac[1] *= clampf(Cc[1] / fmaxf(Ac[1] * s1, 1e-12f), 0.75f, 1.25f);
        Ac[2] *= clampf(Cc[2] / fmaxf(Ac[2] * s2, 1e-12f), 0.75f, 1.25f);
        Ac[3] *= clampf(Cc[3] / fmaxf(Ac[3] * s3, 1e-12f), 0.75f, 1.25f);
        float v[NG];
        #pragma unroll
        for (int g = 0; g < NG; ++g)
            v[g] = y0r[0][g] * Ac[0] + y0r[1][g] * Ac[1]
                 + y0r[2][g] * Ac[2] + y0r[3][g] * Ac[3];
        const float tot = wave_sum32(v, lane);
        const int buf = (q & 1) * (8 * NG);
        if ((lane & 1) == 0) wred[buf + w * NG + g_own] = tot;
        __syncthreads();
        float s = 0.f;
        #pragma unroll
        for (int w2 = 0; w2 < 8; ++w2) s += wred[buf + w2 * NG + g_own];
        Bown *= clampf(Rown / fmaxf(Bown * s, 1e-12f), 0.75f, 1.25f);
    }

    if (!valid) return;

    unsigned pk[NG];
    #pragma unroll
    for (int g = 0; g < NG; ++g) pk[g] = 0u;

    #pragma unroll
    for (int j = 0; j < 4; ++j) {
        float fr[NG];
        int   yv[NG];
        float s = 0.f;
        #pragma unroll
        for (int g = 0; g < NG; ++g) {
            const float z = y0r[j][g] * Ac[j] * readlane_f(Bown, 2 * g);
            fr[g] = z;
            s += z;
        }
        const float F = Cc[j] / fmaxf(s, 1e-12f);
        int isum = 0;
        #pragma unroll
        for (int g = 0; g < NG; ++g) {
            const float y = fr[g] * F;
            const float fl = floorf(y);
            yv[g] = (int)fl;
            fr[g] = y - fl;
            isum += yv[g];
        }
        const int Ci = (int)Cc[j];
        const int need = Ci - isum;
        const int pos = max(need, 0);
        const int q = pos >> 5;
        const int r = pos & 31;
        #pragma unroll
        for (int g = 0; g < NG; ++g) yv[g] += q;
        #pragma unroll
        for (int g = 0; g < NG; ++g) {
            int rank = 0;
            #pragma unroll
            for (int h = 0; h < NG; ++h) {
                if (h == g) continue;
                rank += (h < g) ? (fr[h] >= fr[g] ? 1 : 0) : (fr[h] > fr[g] ? 1 : 0);
            }
            if (rank < r) yv[g] += 1;
        }
        int neg = max(-need, 0);
        neg = min(neg, isum);
        if (__builtin_expect(neg > 0, 0)) {
            const int q2 = neg >> 5;
            int removed = 0;
            #pragma unroll
            for (int g = 0; g < NG; ++g) {
                const int yb = yv[g];
                const int yn = max(yb - q2, 0);
                removed += yb - yn;
                yv[g] = yn;
            }
            const int r2 = neg - removed;
            if (r2 > 0) {
                const float INF = __builtin_inff();
                #pragma unroll
                for (int g = 0; g < NG; ++g) {
                    const float fg = (yv[g] > 0) ? fr[g] : INF;
                    int rank = 0;
                    #pragma unroll
                    for (int h = 0; h < NG; ++h) {
                        if (h == g) continue;
                        const float fh = (yv[h] > 0) ? fr[h] : INF;
                        rank += (h < g) ? (fh <= fg ? 1 : 0) : (fh < fg ? 1 : 0);
                    }
                    if (rank < r2) yv[g] = max(yv[g] - 1, 0);
                }
            }
        }
        #pragma unroll
        for (int g = 0; g < NG; ++g)
            pk[g] |= ((unsigned)yv[g]) << (8 * j);   // yv <= C <= 199 < 256
    }
    #pragma unroll
    for (int g = 0; g < NG; ++g) {
        float* op = &out[1 + (size_t)(b * NG + g) * ND + d0];
        op[0] = (float)(pk[g] & 0xffu);
        op[1] = (float)((pk[g] >> 8) & 0xffu);
        op[2] = (float)((pk[g] >> 16) & 0xffu);
        op[3] = (float)((pk[g] >> 24) & 0xffu);
    }
}

__device__ __forceinline__ void combine_path(
        const float* __restrict__ res2, float* __restrict__ out,
        float* ls, int t) {
    for (int idx = t; idx < NB * 152; idx += 512) {
        const int b = idx / 152, tau = idx - b * 152;
        float s = 0.f;
        #pragma unroll
        for (int c = 0; c < 8; ++c) s += res2[((size_t)b * 8 + c) * 152 + tau];
        ls[idx] = s;
    }
    __syncthreads();
    float v = 0.f;
    if (t < NB) {
        const float* res = &ls[t * 152];
        float conf = 0.f;
        for (int m = 0; m < NM; ++m) conf += sqrtf(res[m]);
        conf *= (1.f / NM);
        float pd = 0.f;
        for (int m = 0; m < NM; ++m) {
            const int offm = 16 + m * NM - m * (m - 1) / 2;
            const float sqm = res[offm];
            for (int n = m + 1; n < NM; ++n) {
                const int offn = 16 + n * NM - n * (n - 1) / 2;
                const float sqn = res[offn];
                const float inn = res[offm + (n - m)];
                pd += sqrtf(fmaxf(sqm + sqn - 2.f * inn, 1e-6f));
            }
        }
        pd = 2.f * pd / (float)(NM * (NM - 1));
        v = (conf - 0.5f * pd) * (1.f / NB);
    }
    if (t < 64) {
        #pragma unroll
        for (int o = 32; o >= 1; o >>= 1) v += __shfl_xor(v, o);
        if (t == 0) out[0] = v;
    }
}

extern "C" __global__ __launch_bounds__(512, 1)
void k_back(const float* __restrict__ xp, const int* __restrict__ tsum,
            const float* __restrict__ res2, float* __restrict__ out) {
    __shared__ float smem[NB * 152];   // 38.9 KB (combine); IPF uses 512 floats
    const int bid = blockIdx.x;
    const int t = threadIdx.x;
    if (bid < NB) {
        ipf_path(xp, tsum, out, smem, bid, t);
    } else {
        combine_path(res2, out, smem, t);
    }
}

// ---------------------------------------------------------------------------
extern "C" void kernel_launch(void* const* d_in, const int* in_sizes, int n_in,
                              void* d_out, int out_size, void* d_ws, size_t ws_size,
                              hipStream_t stream) {
    const float* x     = (const float*)d_in[0];
    const float* tgt   = (const float*)d_in[1];
    const int*   tsum  = (const int*)d_in[2];
    const float* W     = (const float*)d_in[3];
    const float* bias  = (const float*)d_in[4];
    const float* nl    = (const float*)d_in[5];
    const float* nsamp = (const float*)d_in[6];
    float* out = (float*)d_out;

    (void)in_sizes; (void)n_in; (void)out_size; (void)ws_size;

    const size_t XPB = (size_t)2048 * 2000 * 4;        // 16,384,000 B
    float* xp   = (float*)d_ws;
    float* res2 = (float*)((char*)d_ws + XPB);         // 64*8*152 floats

    hipLaunchKernelGGL(k_front, dim3(512), dim3(512), 0, stream,
                       x, nl, tgt, W, bias, nsamp, xp, res2);
    hipLaunchKernelGGL(k_back, dim3(NB + 1), dim3(512), 0, stream,
                       xp, tsum, res2, out);
}